// Round 2
// baseline (170.053 us; speedup 1.0000x reference)
//
#include <hip/hip_runtime.h>
#include <hip/hip_bf16.h>
#include <stdint.h>

#define Hdim 512
#define KC   32768

typedef __hip_bfloat16 bf16;
typedef __attribute__((ext_vector_type(8))) short short8;
typedef __attribute__((ext_vector_type(4))) float float4v;

// async global->LDS, 16B per lane; lds base must be wave-uniform
__device__ __forceinline__ void gl_lds16(const bf16* g, bf16* l) {
  __builtin_amdgcn_global_load_lds(
      (const __attribute__((address_space(1))) unsigned int*)g,
      (__attribute__((address_space(3))) unsigned int*)l,
      16, 0, 0);
}

// pack two fp32 -> two bf16 (truncation) in one v_perm_b32
__device__ __forceinline__ unsigned int pack_bf16_trunc(float e0, float e1) {
  union { float f; unsigned int u; } a, b;
  a.f = e0; b.f = e1;
  // dst = [hi16(src0) : hi16(src1)], src0=b(e1), src1=a(e0) -> low16 = trunc(e0)
  return __builtin_amdgcn_perm(b.u, a.u, 0x07060302u);
}

// ---------------- kernel 1: WT[h][d] = bf16(W[d][h]), tiled ----------------
__global__ void wt_kernel(const float* __restrict__ w, bf16* __restrict__ wt) {
  __shared__ float tile[64][65];
  const int t = threadIdx.x;
  const int tx = t & 63, tw = t >> 6;
  const int d0 = blockIdx.x * 64, h0 = blockIdx.y * 64;
#pragma unroll
  for (int r = 0; r < 16; ++r) {
    int row = r * 4 + tw;
    tile[row][tx] = w[(d0 + row) * Hdim + h0 + tx];
  }
  __syncthreads();
#pragma unroll
  for (int r = 0; r < 16; ++r) {
    int row = r * 4 + tw;  // h-local
    wt[(size_t)(h0 + row) * Hdim + d0 + tx] = __float2bfloat16(tile[tx][row]);
  }
}

// ---------------- kernel 2: gates + alpha_wi (fp32 matvecs) ----------------
// 32 blocks x 256. Block b: outputs j0=b*64 (j<1536: gates, else awi). 1536%64==0.
__global__ void prep_kernel(const float* __restrict__ input_, const float* __restrict__ h_0,
                            const float* __restrict__ w_ih, const float* __restrict__ w_hh,
                            const float* __restrict__ bias, const float* __restrict__ a_w_ih,
                            float* __restrict__ gates, float* __restrict__ awi) {
  __shared__ float inf_[Hdim], h0f[Hdim];
  __shared__ float red[4][64];
  const int t = threadIdx.x;
  const int lane = t & 63, wv = t >> 6;
  for (int i = t; i < Hdim; i += 256) { inf_[i] = input_[i]; h0f[i] = h_0[i]; }
  __syncthreads();
  const int j0 = blockIdx.x * 64;
  float acc = 0.f;
  if (j0 < 3 * Hdim) {
    const int j = j0 + lane;
    for (int d = wv * 128; d < wv * 128 + 128; ++d)
      acc += h0f[d] * w_hh[d * 3 * Hdim + j] + inf_[d] * w_ih[d * 3 * Hdim + j];
  } else {
    const int j = j0 - 3 * Hdim + lane;
    for (int d = wv * 128; d < wv * 128 + 128; ++d)
      acc += inf_[d] * a_w_ih[d * Hdim + j];
  }
  red[wv][lane] = acc;
  __syncthreads();
  if (t < 64) {
    float s = red[0][t] + red[1][t] + red[2][t] + red[3][t];
    if (j0 < 3 * Hdim) gates[j0 + t] = s + bias[j0 + t];
    else               awi[j0 - 3 * Hdim + t] = s;
  }
}

// ---------------- kernel 3: fused GEMM + sigmoid/exp + K-partial reduction ----------------
// grid: (KC/128, Hdim/128), 256 threads (4 waves, 2x2)
__global__ __launch_bounds__(256) void gemm_reduce_kernel(
    const float* __restrict__ c_input, const bf16* __restrict__ WT,
    const float* __restrict__ awi,
    float* __restrict__ pw, float* __restrict__ pwc) {
  __shared__ __align__(16) bf16 As[128 * 64];   // [kk][d]
  __shared__ __align__(16) bf16 Bs[128 * 64];   // [h][d] (rows of W^T)
  __shared__ float red_w[2][128];
  __shared__ float red_wc[2][128];

  const int tid  = threadIdx.x;
  const int lane = tid & 63;
  const int wave = tid >> 6;
  const int wm   = wave & 1;
  const int wn   = wave >> 1;
  const int lm   = lane & 15;
  const int lq   = lane >> 4;

  const int kk0 = blockIdx.x * 128;
  const int h0  = blockIdx.y * 128;

  float4v acc[4][4];
#pragma unroll
  for (int i = 0; i < 4; ++i)
#pragma unroll
    for (int j = 0; j < 4; ++j)
      acc[i][j] = (float4v){0.f, 0.f, 0.f, 0.f};

  const int ldrow = wave * 8 + (lane >> 3);
  const int ldcol = (lane & 7) * 8;

  for (int d0 = 0; d0 < Hdim; d0 += 64) {
    // B tile: bf16 W^T rows via async global->LDS (16B/lane)
#pragma unroll
    for (int r = 0; r < 4; ++r)
      gl_lds16(WT + (size_t)(h0 + r * 32 + ldrow) * Hdim + d0 + ldcol,
               Bs + (r * 32 + wave * 8) * 64);
    // A tile: fp32 load -> trunc bf16 -> LDS. f = float4 index (16 per row).
#pragma unroll
    for (int j = 0; j < 8; ++j) {
      const int f = j * 256 + tid;
      float4v v = *(const float4v*)(c_input + (size_t)(kk0 + (f >> 4)) * Hdim + d0 + (f & 15) * 4);
      unsigned long long p = (unsigned long long)pack_bf16_trunc(v[0], v[1])
                           | ((unsigned long long)pack_bf16_trunc(v[2], v[3]) << 32);
      *(unsigned long long*)(As + (size_t)f * 4) = p;  // ds_write_b64 at byte f*8
    }
    __builtin_amdgcn_s_waitcnt(0x0f70);  // vmcnt(0): B async loads done
    __syncthreads();                      // + lgkmcnt for ds_writes

#pragma unroll
    for (int ks = 0; ks < 2; ++ks) {
      short8 a[4], b[4];
#pragma unroll
      for (int mt = 0; mt < 4; ++mt)
        a[mt] = *(const short8*)(As + (wm * 64 + mt * 16 + lm) * 64 + ks * 32 + lq * 8);
#pragma unroll
      for (int nt = 0; nt < 4; ++nt)
        b[nt] = *(const short8*)(Bs + (wn * 64 + nt * 16 + lm) * 64 + ks * 32 + lq * 8);
#pragma unroll
      for (int mt = 0; mt < 4; ++mt)
#pragma unroll
        for (int nt = 0; nt < 4; ++nt)
          acc[mt][nt] = __builtin_amdgcn_mfma_f32_16x16x32_bf16(a[mt], b[nt], acc[mt][nt], 0, 0, 0);
    }
    __syncthreads();
  }

  // epilogue: alpha = sigmoid(acc + awi[h]); accumulate exp(alpha), exp(alpha)*c
  float awi_l[4];
#pragma unroll
  for (int nt = 0; nt < 4; ++nt)
    awi_l[nt] = awi[h0 + wn * 64 + nt * 16 + lm];

  float sw[4] = {0.f, 0.f, 0.f, 0.f}, swc[4] = {0.f, 0.f, 0.f, 0.f};
#pragma unroll
  for (int nt = 0; nt < 4; ++nt) {
    const int h = h0 + wn * 64 + nt * 16 + lm;
#pragma unroll
    for (int mt = 0; mt < 4; ++mt) {
      const int kkb = kk0 + wm * 64 + mt * 16 + lq * 4;
#pragma unroll
      for (int r = 0; r < 4; ++r) {
        float v = acc[mt][nt][r] + awi_l[nt];
        float aval = 1.f / (1.f + __expf(-v));
        float e = __expf(aval);
        float c = c_input[(size_t)(kkb + r) * Hdim + h];  // fp32 exact, LLC-warm
        sw[nt]  += e;
        swc[nt] += e * c;
      }
    }
  }
#pragma unroll
  for (int nt = 0; nt < 4; ++nt) {
    sw[nt]  += __shfl_xor(sw[nt], 16, 64);
    sw[nt]  += __shfl_xor(sw[nt], 32, 64);
    swc[nt] += __shfl_xor(swc[nt], 16, 64);
    swc[nt] += __shfl_xor(swc[nt], 32, 64);
  }
  if (lq == 0) {
#pragma unroll
    for (int nt = 0; nt < 4; ++nt) {
      red_w[wm][wn * 64 + nt * 16 + lm]  = sw[nt];
      red_wc[wm][wn * 64 + nt * 16 + lm] = swc[nt];
    }
  }
  __syncthreads();
  if (tid < 128) {
    pw[(size_t)blockIdx.x * Hdim + h0 + tid]  = red_w[0][tid] + red_w[1][tid];
    pwc[(size_t)blockIdx.x * Hdim + h0 + tid] = red_wc[0][tid] + red_wc[1][tid];
  }
}

// ---------------- kernel 4: final reduction + LSTM merge ----------------
__global__ void finalize_kernel(const float* __restrict__ pw, const float* __restrict__ pwc,
                                const float* __restrict__ gates, float* __restrict__ out) {
  int hh = blockIdx.x * 64 + threadIdx.x;  // 0..511
  float sw = 0.f, swc = 0.f;
  for (int kb = 0; kb < KC / 128; ++kb) {
    sw  += pw[(size_t)kb * Hdim + hh];
    swc += pwc[(size_t)kb * Hdim + hh];
  }
  float ipre = gates[hh], opre = gates[Hdim + hh], gpre = gates[2 * Hdim + hh];
  float ei = expf(1.f / (1.f + expf(-ipre)));   // exp(sigmoid(i))
  float g  = tanhf(gpre);
  float o  = 1.f / (1.f + expf(-opre));
  float denom = ei + sw + 1e-12f;
  float c1 = (ei * g + swc) / denom;
  float h1 = o * tanhf(c1);
  out[hh]        = h1;
  out[Hdim + hh] = c1;
}

extern "C" void kernel_launch(void* const* d_in, const int* in_sizes, int n_in,
                              void* d_out, int out_size, void* d_ws, size_t ws_size,
                              hipStream_t stream) {
  const float* input_  = (const float*)d_in[0];
  const float* c_input = (const float*)d_in[1];
  const float* h_0     = (const float*)d_in[2];
  /* d_in[3] = c_0, unused by the reference's taken branch */
  const float* w_ih    = (const float*)d_in[4];
  const float* w_hh    = (const float*)d_in[5];
  const float* bias    = (const float*)d_in[6];
  const float* a_w_ih  = (const float*)d_in[7];
  const float* a_w_hh  = (const float*)d_in[8];

  char* ws = (char*)d_ws;
  float* pw    = (float*)ws;                          // 256*512 f32 = 512 KB
  float* pwc   = (float*)(ws + 512 * 1024);           // 512 KB
  float* gates = (float*)(ws + 1024 * 1024);          // 6 KB
  float* awi   = (float*)(ws + 1024 * 1024 + 8192);   // 2 KB
  bf16*  WT    = (bf16*)(ws + 1024 * 1024 + 16384);   // 512 KB

  hipLaunchKernelGGL(wt_kernel, dim3(8, 8), dim3(256), 0, stream, a_w_hh, WT);
  hipLaunchKernelGGL(prep_kernel, dim3(32), dim3(256), 0, stream,
                     input_, h_0, w_ih, w_hh, bias, a_w_ih, gates, awi);
  hipLaunchKernelGGL(gemm_reduce_kernel, dim3(KC / 128, Hdim / 128), dim3(256), 0, stream,
                     c_input, WT, awi, pw, pwc);
  hipLaunchKernelGGL(finalize_kernel, dim3(8), dim3(64), 0, stream,
                     pw, pwc, gates, (float*)d_out);
}

// Round 3
// 152.571 us; speedup vs baseline: 1.1146x; 1.1146x over previous
//
#include <hip/hip_runtime.h>
#include <hip/hip_bf16.h>
#include <stdint.h>

#define Hdim 512
#define KC   32768

typedef __hip_bfloat16 bf16;
typedef __attribute__((ext_vector_type(8))) short short8;
typedef __attribute__((ext_vector_type(4))) float float4v;

// pack two fp32 -> two bf16 (truncation) in one v_perm_b32
__device__ __forceinline__ unsigned int pack_bf16_trunc(float e0, float e1) {
  union { float f; unsigned int u; } a, b;
  a.f = e0; b.f = e1;
  return __builtin_amdgcn_perm(b.u, a.u, 0x07060302u);  // [hi16(e1):hi16(e0)]
}

// ---------------- launch 1: prep (blocks 0..127) + WT transpose (blocks 128..191) ----
__global__ __launch_bounds__(256) void prep_wt_kernel(
    const float* __restrict__ input_, const float* __restrict__ h_0,
    const float* __restrict__ w_ih, const float* __restrict__ w_hh,
    const float* __restrict__ a_w_ih, const float* __restrict__ a_w_hh,
    float* __restrict__ gates, float* __restrict__ awi, bf16* __restrict__ wt) {
  __shared__ float sh[64 * 65];   // wt tile / prep scratch
  const int t = threadIdx.x;
  if (blockIdx.x < 128) {
    // prep: 32 j-tiles (64 wide over 2048 virtual outputs) x 4 d-chunks (128 deep)
    const int b  = blockIdx.x;
    const int jt = b & 31, dc = b >> 5;
    const int lane = t & 63, wv = t >> 6;
    float* h0s = sh;         // 128
    float* ins = sh + 128;   // 128
    float* red = sh + 256;   // 256
    if (t < 128) { h0s[t] = h_0[dc * 128 + t]; ins[t] = input_[dc * 128 + t]; }
    __syncthreads();
    float acc = 0.f;
    if (jt < 24) {
      const int j = jt * 64 + lane;
#pragma unroll 4
      for (int i = 0; i < 32; ++i) {
        const int dl = wv * 32 + i;
        const size_t d = dc * 128 + dl;
        acc += h0s[dl] * w_hh[d * 1536 + j] + ins[dl] * w_ih[d * 1536 + j];
      }
    } else {
      const int j = (jt - 24) * 64 + lane;
#pragma unroll 4
      for (int i = 0; i < 32; ++i) {
        const int dl = wv * 32 + i;
        const size_t d = dc * 128 + dl;
        acc += ins[dl] * a_w_ih[d * Hdim + j];
      }
    }
    red[wv * 64 + lane] = acc;
    __syncthreads();
    if (t < 64) {
      float s = red[t] + red[64 + t] + red[128 + t] + red[192 + t];
      if (jt < 24) atomicAdd(&gates[jt * 64 + t], s);
      else         atomicAdd(&awi[(jt - 24) * 64 + t], s);
    }
  } else {
    // WT[h][d] = bf16(W[d][h])
    const int b = blockIdx.x - 128;
    const int d0 = (b & 7) * 64, h0 = (b >> 3) * 64;
    const int tx = t & 63, tw = t >> 6;
    float (*tile)[65] = (float (*)[65])sh;
#pragma unroll
    for (int r = 0; r < 16; ++r) {
      const int row = r * 4 + tw;
      tile[row][tx] = a_w_hh[(size_t)(d0 + row) * Hdim + h0 + tx];
    }
    __syncthreads();
#pragma unroll
    for (int r = 0; r < 16; ++r) {
      const int row = r * 4 + tw;
      wt[(size_t)(h0 + row) * Hdim + d0 + tx] = __float2bfloat16(tile[tx][row]);
    }
  }
}

// ---------------- launch 2: fused GEMM + sigmoid/exp + K-partial reduction ----------------
// 1024 blocks (XCD-swizzled), 256 threads (4 waves, 2x2). LDS granule-XOR swizzle.
__global__ __launch_bounds__(256) void gemm_reduce_kernel(
    const float* __restrict__ c_input, const bf16* __restrict__ WT,
    const float* __restrict__ awi,
    float* __restrict__ pw, float* __restrict__ pwc) {
  __shared__ __align__(16) bf16 As[128 * 64];   // swizzled [row][g^(row&7)]
  __shared__ __align__(16) bf16 Bs[128 * 64];   // swizzled
  __shared__ float red_w[2][128];
  __shared__ float red_wc[2][128];

  const int tid  = threadIdx.x;
  const int lane = tid & 63;
  const int wave = tid >> 6;
  const int wm   = wave & 1;
  const int wn   = wave >> 1;
  const int lm   = lane & 15;
  const int lq   = lane >> 4;

  // XCD swizzle: the 4 h-blocks of one kk-slab share (id&7) -> same XCD, adjacent ids
  const int id     = blockIdx.x;
  const int kk_idx = ((id >> 5) << 3) | (id & 7);
  const int h_idx  = (id >> 3) & 3;
  const int kk0 = kk_idx * 128;
  const int h0  = h_idx * 128;

  float4v acc[4][4];
#pragma unroll
  for (int i = 0; i < 4; ++i)
#pragma unroll
    for (int j = 0; j < 4; ++j)
      acc[i][j] = (float4v){0.f, 0.f, 0.f, 0.f};

  char* AsB = (char*)As;
  char* BsB = (char*)Bs;

  for (int d0 = 0; d0 < Hdim; d0 += 64) {
    // A tile: fp32 -> trunc bf16 -> swizzled LDS (8B units)
#pragma unroll
    for (int j = 0; j < 8; ++j) {
      const int f = j * 256 + tid;
      const int row = f >> 4, sub = f & 15;
      float4v v = *(const float4v*)(c_input + (size_t)(kk0 + row) * Hdim + d0 + sub * 4);
      unsigned long long p = (unsigned long long)pack_bf16_trunc(v[0], v[1])
                           | ((unsigned long long)pack_bf16_trunc(v[2], v[3]) << 32);
      *(unsigned long long*)(AsB + row * 128 + (((sub >> 1) ^ (row & 7)) * 16) + (sub & 1) * 8) = p;
    }
    // B tile: bf16 16B granules -> swizzled LDS
#pragma unroll
    for (int r = 0; r < 4; ++r) {
      const int row = r * 32 + wave * 8 + (lane >> 3);
      const int g   = lane & 7;
      short8 wv8 = *(const short8*)(WT + (size_t)(h0 + row) * Hdim + d0 + g * 8);
      *(short8*)(BsB + row * 128 + ((g ^ (lane >> 3)) * 16)) = wv8;
    }
    __syncthreads();

#pragma unroll
    for (int ks = 0; ks < 2; ++ks) {
      short8 a[4], b[4];
#pragma unroll
      for (int mt = 0; mt < 4; ++mt) {
        const int row = wm * 64 + mt * 16 + lm;
        a[mt] = *(const short8*)(AsB + row * 128 + (((ks * 4 + lq) ^ (lm & 7)) * 16));
      }
#pragma unroll
      for (int nt = 0; nt < 4; ++nt) {
        const int row = wn * 64 + nt * 16 + lm;
        b[nt] = *(const short8*)(BsB + row * 128 + (((ks * 4 + lq) ^ (lm & 7)) * 16));
      }
#pragma unroll
      for (int mt = 0; mt < 4; ++mt)
#pragma unroll
        for (int nt = 0; nt < 4; ++nt)
          acc[mt][nt] = __builtin_amdgcn_mfma_f32_16x16x32_bf16(a[mt], b[nt], acc[mt][nt], 0, 0, 0);
    }
    __syncthreads();
  }

  // epilogue: alpha = sigmoid(acc + awi[h]); accumulate exp(alpha), exp(alpha)*c
  float awi_l[4];
#pragma unroll
  for (int nt = 0; nt < 4; ++nt)
    awi_l[nt] = awi[h0 + wn * 64 + nt * 16 + lm];

  float sw[4] = {0.f, 0.f, 0.f, 0.f}, swc[4] = {0.f, 0.f, 0.f, 0.f};
#pragma unroll
  for (int nt = 0; nt < 4; ++nt) {
    const int h = h0 + wn * 64 + nt * 16 + lm;
#pragma unroll
    for (int mt = 0; mt < 4; ++mt) {
      const int kkb = kk0 + wm * 64 + mt * 16 + lq * 4;
#pragma unroll
      for (int r = 0; r < 4; ++r) {
        float v = acc[mt][nt][r] + awi_l[nt];
        float aval = 1.f / (1.f + __expf(-v));
        float e = __expf(aval);
        float c = c_input[(size_t)(kkb + r) * Hdim + h];  // L2-hot after GEMM pass
        sw[nt]  += e;
        swc[nt] += e * c;
      }
    }
  }
#pragma unroll
  for (int nt = 0; nt < 4; ++nt) {
    sw[nt]  += __shfl_xor(sw[nt], 16, 64);
    sw[nt]  += __shfl_xor(sw[nt], 32, 64);
    swc[nt] += __shfl_xor(swc[nt], 16, 64);
    swc[nt] += __shfl_xor(swc[nt], 32, 64);
  }
  if (lq == 0) {
#pragma unroll
    for (int nt = 0; nt < 4; ++nt) {
      red_w[wm][wn * 64 + nt * 16 + lm]  = sw[nt];
      red_wc[wm][wn * 64 + nt * 16 + lm] = swc[nt];
    }
  }
  __syncthreads();
  if (tid < 128) {
    pw[(size_t)kk_idx * Hdim + h0 + tid]  = red_w[0][tid] + red_w[1][tid];
    pwc[(size_t)kk_idx * Hdim + h0 + tid] = red_wc[0][tid] + red_wc[1][tid];
  }
}

// ---------------- launch 3: final reduction + LSTM merge ----------------
__global__ __launch_bounds__(256) void finalize_kernel(
    const float* __restrict__ pw, const float* __restrict__ pwc,
    const float* __restrict__ gates, const float* __restrict__ bias,
    float* __restrict__ out) {
  __shared__ float rsw[4][64], rswc[4][64];
  const int t = threadIdx.x;
  const int hl = t & 63, q = t >> 6;
  const int hh = blockIdx.x * 64 + hl;
  float sw = 0.f, swc = 0.f;
#pragma unroll 4
  for (int kb = q * 64; kb < q * 64 + 64; ++kb) {
    sw  += pw[(size_t)kb * Hdim + hh];
    swc += pwc[(size_t)kb * Hdim + hh];
  }
  rsw[q][hl] = sw; rswc[q][hl] = swc;
  __syncthreads();
  if (t < 64) {
    const int h = blockIdx.x * 64 + t;
    sw  = rsw[0][t] + rsw[1][t] + rsw[2][t] + rsw[3][t];
    swc = rswc[0][t] + rswc[1][t] + rswc[2][t] + rswc[3][t];
    float ipre = gates[h] + bias[h];
    float opre = gates[Hdim + h] + bias[Hdim + h];
    float gpre = gates[2 * Hdim + h] + bias[2 * Hdim + h];
    float ei = expf(1.f / (1.f + expf(-ipre)));   // exp(sigmoid(i))
    float g  = tanhf(gpre);
    float o  = 1.f / (1.f + expf(-opre));
    float denom = ei + sw + 1e-12f;
    float c1 = (ei * g + swc) / denom;
    float h1 = o * tanhf(c1);
    out[h]        = h1;
    out[Hdim + h] = c1;
  }
}

extern "C" void kernel_launch(void* const* d_in, const int* in_sizes, int n_in,
                              void* d_out, int out_size, void* d_ws, size_t ws_size,
                              hipStream_t stream) {
  const float* input_  = (const float*)d_in[0];
  const float* c_input = (const float*)d_in[1];
  const float* h_0     = (const float*)d_in[2];
  /* d_in[3] = c_0: unused by the reference's taken branch */
  const float* w_ih    = (const float*)d_in[4];
  const float* w_hh    = (const float*)d_in[5];
  const float* bias    = (const float*)d_in[6];
  const float* a_w_ih  = (const float*)d_in[7];
  const float* a_w_hh  = (const float*)d_in[8];

  char* ws = (char*)d_ws;
  float* pw    = (float*)ws;                          // 256*512 f32 = 512 KB
  float* pwc   = (float*)(ws + 512 * 1024);           // 512 KB
  float* gates = (float*)(ws + 1024 * 1024);          // 6 KB
  float* awi   = (float*)(ws + 1024 * 1024 + 6144);   // 2 KB
  bf16*  WT    = (bf16*)(ws + 1024 * 1024 + 8192);    // 512 KB

  hipMemsetAsync(ws + 1024 * 1024, 0, 8192, stream);  // zero gates+awi (atomics)
  hipLaunchKernelGGL(prep_wt_kernel, dim3(192), dim3(256), 0, stream,
                     input_, h_0, w_ih, w_hh, a_w_ih, a_w_hh, gates, awi, WT);
  hipLaunchKernelGGL(gemm_reduce_kernel, dim3(1024), dim3(256), 0, stream,
                     c_input, WT, awi, pw, pwc);
  hipLaunchKernelGGL(finalize_kernel, dim3(8), dim3(256), 0, stream,
                     pw, pwc, gates, bias, (float*)d_out);
}